// Round 1
// 1913.960 us; speedup vs baseline: 1.1150x; 1.1150x over previous
//
#include <hip/hip_runtime.h>
#include <hip/hip_bf16.h>

#define NG 50000
#define NU 200000
#define DIM 128
#define NNZ 2000000
#define LAYERS 3

// bucket geometry for the binned counting sort
#define RB_SHIFT 7                      // 128 rows per bucket
#define CB_SHIFT 9                      // 512 cols per bucket
#define NBR ((NG + 127) / 128)          // 391
#define NBC ((NU + 511) / 512)          // 391
#define BIN_K 32                        // edges per thread in k_bin (8192/block)

// ---------------- preprocessing: histogram + scan --------------------------

__global__ __launch_bounds__(256) void k_hist(const int* __restrict__ rows,
                                              const int* __restrict__ cols,
                                              int* __restrict__ row_ptr,
                                              int* __restrict__ col_ptr, int nnz) {
    int e = blockIdx.x * 256 + threadIdx.x;
    if (e < nnz) {
        atomicAdd(&row_ptr[rows[e] + 1], 1);
        atomicAdd(&col_ptr[cols[e] + 1], 1);
    }
}

// inclusive scan, 256 per block; partials[b] = block total
__global__ __launch_bounds__(256) void k_scan1(int* __restrict__ a, int n,
                                               int* __restrict__ partials) {
    __shared__ int s[256];
    int t = threadIdx.x;
    int i = blockIdx.x * 256 + t;
    s[t] = (i < n) ? a[i] : 0;
    __syncthreads();
    for (int off = 1; off < 256; off <<= 1) {
        int x = (t >= off) ? s[t - off] : 0;
        __syncthreads();
        s[t] += x;
        __syncthreads();
    }
    if (i < n) a[i] = s[t];
    if (t == 255) partials[blockIdx.x] = s[255];
}

__global__ __launch_bounds__(1024) void k_scan2(int* __restrict__ partials, int nb) {
    __shared__ int s[1024];
    int t = threadIdx.x;
    s[t] = (t < nb) ? partials[t] : 0;
    __syncthreads();
    for (int off = 1; off < 1024; off <<= 1) {
        int x = (t >= off) ? s[t - off] : 0;
        __syncthreads();
        s[t] += x;
        __syncthreads();
    }
    if (t < nb) partials[t] = s[t];
}

__global__ __launch_bounds__(256) void k_scan3(int* __restrict__ a, int n,
                                               const int* __restrict__ partials) {
    int b = blockIdx.x;
    if (b == 0) return;
    int i = b * 256 + threadIdx.x;
    if (i < n) a[i] += partials[b - 1];
}

// seed per-bucket global fill pointers from the CSR/CSC ptr arrays
__global__ __launch_bounds__(512) void k_initfill(const int* __restrict__ row_ptr,
                                                  const int* __restrict__ col_ptr,
                                                  int* __restrict__ fillR,
                                                  int* __restrict__ fillC) {
    int t = threadIdx.x;
    if (t < NBR) fillR[t] = row_ptr[t << RB_SHIFT];
    if (t < NBC) fillC[t] = col_ptr[t << CB_SHIFT];
}

// ---- pass 1: bin edges into bucket-contiguous staging arrays --------------
// binR entry: .x = (local_row<<18)|col  .y = valbits   (7+18 bits, fits)
// binC entry: .x = (local_col<<16)|row  .y = valbits   (9+16 bits, fits)
__global__ __launch_bounds__(256) void k_bin(const int* __restrict__ rows,
                                             const int* __restrict__ cols,
                                             const float* __restrict__ vals,
                                             int* __restrict__ fillR,
                                             int* __restrict__ fillC,
                                             int2* __restrict__ binR,
                                             int2* __restrict__ binC, int nnz) {
    __shared__ int cR[NBR];
    __shared__ int cC[NBC];
    int t = threadIdx.x;
    int base = blockIdx.x * (256 * BIN_K);
    for (int i = t; i < NBR; i += 256) cR[i] = 0;
    for (int i = t; i < NBC; i += 256) cC[i] = 0;
    __syncthreads();
    // count
    for (int k = 0; k < BIN_K; k++) {
        int e = base + k * 256 + t;
        if (e < nnz) {
            atomicAdd(&cR[rows[e] >> RB_SHIFT], 1);
            atomicAdd(&cC[cols[e] >> CB_SHIFT], 1);
        }
    }
    __syncthreads();
    // reserve contiguous runs in the bucket regions; repurpose cR/cC as
    // running global positions
    for (int b = t; b < NBR; b += 256) {
        int n = cR[b];
        cR[b] = n ? atomicAdd(&fillR[b], n) : 0;
    }
    for (int b = t; b < NBC; b += 256) {
        int n = cC[b];
        cC[b] = n ? atomicAdd(&fillC[b], n) : 0;
    }
    __syncthreads();
    // write
    for (int k = 0; k < BIN_K; k++) {
        int e = base + k * 256 + t;
        if (e < nnz) {
            int r = rows[e], c = cols[e];
            int v = __float_as_int(vals[e]);
            int pR = atomicAdd(&cR[r >> RB_SHIFT], 1);
            binR[pR] = make_int2(((r & 127) << 18) | c, v);
            int pC = atomicAdd(&cC[c >> CB_SHIFT], 1);
            binC[pC] = make_int2(((c & 511) << 16) | r, v);
        }
    }
}

// ---- pass 2: within each bucket, scatter to final per-row position --------
// one block per bucket; all writes land inside the bucket's ~40KB region
// which this block fills completely -> full-line writebacks.
__global__ __launch_bounds__(256) void k_unbin(const int* __restrict__ row_ptr,
                                               const int* __restrict__ col_ptr,
                                               const int2* __restrict__ binR,
                                               const int2* __restrict__ binC,
                                               int2* __restrict__ r_edges,
                                               int2* __restrict__ c_edges) {
    __shared__ int pos[512];
    int t = threadIdx.x;
    int b = blockIdx.x;
    if (b < NBR) {
        int r0 = b << RB_SHIFT;
        int nr = min(128, NG - r0);
        if (t < nr) pos[t] = row_ptr[r0 + t];
        __syncthreads();
        int lo = row_ptr[r0];
        int hi = row_ptr[r0 + nr];
        for (int i = lo + t; i < hi; i += 256) {
            int2 e = binR[i];
            int lr = e.x >> 18;
            int c = e.x & 0x3FFFF;
            int p = atomicAdd(&pos[lr], 1);
            r_edges[p] = make_int2(c, e.y);
        }
    } else {
        int c0 = (b - NBR) << CB_SHIFT;
        int nc = min(512, NU - c0);
        for (int i = t; i < nc; i += 256) pos[i] = col_ptr[c0 + i];
        __syncthreads();
        int lo = col_ptr[c0];
        int hi = col_ptr[c0 + nc];
        for (int i = lo + t; i < hi; i += 256) {
            int2 e = binC[i];
            int lc = e.x >> 16;
            int r = e.x & 0xFFFF;
            int p = atomicAdd(&pos[lc], 1);
            c_edges[p] = make_int2(r, e.y);
        }
    }
}

// ---------------- SpMM: one wave per output row, float2 per lane -------------
// out[w] = sum_e val[e] * x[idx[e]]   (edges grouped by w via counting sort)
// optional fused: sum_out[w] = (sum_init ? sum_init[w] : sum_out[w]) + acc

__global__ __launch_bounds__(256) void k_spmm(const int* __restrict__ ptr,
                                              const int2* __restrict__ edges,
                                              const float* __restrict__ x,
                                              float* __restrict__ out,
                                              const float* __restrict__ sum_init,
                                              float* __restrict__ sum_out,
                                              int nrows) {
    int w = blockIdx.x * 4 + (threadIdx.x >> 6);
    int lane = threadIdx.x & 63;
    if (w >= nrows) return;
    int beg = ptr[w], end = ptr[w + 1];
    float a0 = 0.f, a1 = 0.f;
    for (int base = beg; base < end; base += 64) {
        int n = end - base;
        if (n > 64) n = 64;
        int2 e = make_int2(0, 0);
        if (lane < n) e = edges[base + lane];
        int j = 0;
        for (; j + 4 <= n; j += 4) {
            int c0 = __shfl(e.x, j);     float v0 = __int_as_float(__shfl(e.y, j));
            int c1 = __shfl(e.x, j + 1); float v1 = __int_as_float(__shfl(e.y, j + 1));
            int c2 = __shfl(e.x, j + 2); float v2 = __int_as_float(__shfl(e.y, j + 2));
            int c3 = __shfl(e.x, j + 3); float v3 = __int_as_float(__shfl(e.y, j + 3));
            float2 x0 = *((const float2*)(x + (size_t)c0 * DIM) + lane);
            float2 x1 = *((const float2*)(x + (size_t)c1 * DIM) + lane);
            float2 x2 = *((const float2*)(x + (size_t)c2 * DIM) + lane);
            float2 x3 = *((const float2*)(x + (size_t)c3 * DIM) + lane);
            a0 += v0 * x0.x; a1 += v0 * x0.y;
            a0 += v1 * x1.x; a1 += v1 * x1.y;
            a0 += v2 * x2.x; a1 += v2 * x2.y;
            a0 += v3 * x3.x; a1 += v3 * x3.y;
        }
        for (; j < n; j++) {
            int c = __shfl(e.x, j);
            float v = __int_as_float(__shfl(e.y, j));
            float2 xv = *((const float2*)(x + (size_t)c * DIM) + lane);
            a0 += v * xv.x; a1 += v * xv.y;
        }
    }
    size_t o2 = (size_t)w * (DIM / 2) + lane;  // float2 index
    if (out) ((float2*)out)[o2] = make_float2(a0, a1);
    if (sum_out) {
        float2 s;
        if (sum_init) s = ((const float2*)sum_init)[o2];
        else          s = ((const float2*)sum_out)[o2];
        s.x += a0;
        s.y += a1;
        ((float2*)sum_out)[o2] = s;
    }
}

// ---- gated GEMM: msg = concat(nm, nm*grp) @ W + b ;
//      edge_sum = (edge_init ? edge_init : edge_sum) + msg ---------------------
// block = 256 threads, 64 group rows per block, 4 K-chunks of 64.
// NOTE: group_cur and msg_out may alias (each block reads only its own rows,
// all reads happen before the epilogue write) -> no __restrict__ on those.

__global__ __launch_bounds__(256) void k_gemm_gate(const float* __restrict__ node_msg,
                                                   const float* group_cur,
                                                   const float* __restrict__ W,
                                                   const float* __restrict__ bias,
                                                   float* msg_out,
                                                   const float* __restrict__ edge_init,
                                                   float* __restrict__ edge_sum, int ng) {
    __shared__ float Ws[64][128];
    __shared__ float Xs[64][64];
    int t = threadIdx.x;
    int col = t & 127;
    int rhalf = t >> 7;  // 0 or 1
    int g0 = blockIdx.x * 64;

    float acc[32];
#pragma unroll
    for (int r = 0; r < 32; r++) acc[r] = 0.f;

    for (int kc = 0; kc < 4; kc++) {
        int k0 = kc * 64;
        // W chunk: rows [k0, k0+64) x 128 cols
        for (int i = t; i < 64 * 128; i += 256)
            Ws[i >> 7][i & 127] = W[(k0 + (i >> 7)) * 128 + (i & 127)];
        // X chunk: 64 rows x 64 k (gate computed inline)
        for (int i = t; i < 64 * 64; i += 256) {
            int r = i >> 6;
            int k = k0 + (i & 63);
            int g = g0 + r;
            float v = 0.f;
            if (g < ng) {
                if (k < 128) v = node_msg[g * DIM + k];
                else {
                    int kk = k - 128;
                    v = node_msg[g * DIM + kk] * group_cur[g * DIM + kk];
                }
            }
            Xs[r][i & 63] = v;
        }
        __syncthreads();
        for (int k = 0; k < 64; k++) {
            float w = Ws[k][col];
#pragma unroll
            for (int r = 0; r < 32; r++)
                acc[r] += Xs[2 * r + rhalf][k] * w;
        }
        __syncthreads();
    }

    float b = bias[col];
#pragma unroll
    for (int r = 0; r < 32; r++) {
        int g = g0 + 2 * r + rhalf;
        if (g < ng) {
            int idx = g * DIM + col;
            float v = acc[r] + b;
            float es = edge_init ? edge_init[idx] : edge_sum[idx];
            msg_out[idx] = v;
            edge_sum[idx] = es + v;
        }
    }
}

// ---------------------------------------------------------------------------

extern "C" void kernel_launch(void* const* d_in, const int* in_sizes, int n_in,
                              void* d_out, int out_size, void* d_ws, size_t ws_size,
                              hipStream_t stream) {
    const float* group_emb = (const float*)d_in[0];  // [NG,128]
    const float* user_emb  = (const float*)d_in[1];  // [NU,128]
    const int*   rows      = (const int*)d_in[2];    // [NNZ]
    const int*   cols      = (const int*)d_in[3];    // [NNZ]
    const float* vals      = (const float*)d_in[4];  // [NNZ]
    const float* Ws        = (const float*)d_in[5];  // [3,256,128]
    const float* bs        = (const float*)d_in[6];  // [3,128]

    float* node_sum = (float*)d_out;                 // [NU,128]
    float* edge_sum = (float*)d_out + (size_t)NU * DIM;  // [NG,128]

    // workspace carve (16B aligned)
    char* p = (char*)d_ws;
    auto carve = [&](size_t bytes) {
        void* r = (void*)p;
        p += (bytes + 15) & ~(size_t)15;
        return r;
    };
    float* U        = (float*)carve((size_t)NU * DIM * 4);   // user ping buffer
    float* M        = (float*)carve((size_t)NG * DIM * 4);   // msg buffer
    float* node_msg = (float*)carve((size_t)NG * DIM * 4);
    int*   row_ptr  = (int*)carve((NG + 1) * 4);
    int*   col_ptr  = (int*)carve((NU + 1) * 4);
    int*   fillR    = (int*)carve(NBR * 4);
    int*   fillC    = (int*)carve(NBC * 4);
    int2*  r_edges  = (int2*)carve((size_t)NNZ * 8);
    int2*  c_edges  = (int2*)carve((size_t)NNZ * 8);
    int*   partials = (int*)carve(1024 * 4);

    // binned staging buffers alias U: U is not live until the first layer,
    // and preprocessing finishes before the layers start. 2*NNZ*8 = 32MB
    // fits comfortably inside U's 102.4MB.
    int2* binR = (int2*)U;
    int2* binC = binR + NNZ;

    // --- build CSR (row-sorted) and CSC (col-sorted) packed edge lists ---
    hipMemsetAsync(row_ptr, 0, (NG + 1) * 4, stream);
    hipMemsetAsync(col_ptr, 0, (NU + 1) * 4, stream);

    k_hist<<<(NNZ + 255) / 256, 256, 0, stream>>>(rows, cols, row_ptr, col_ptr, NNZ);

    {   // scan row_ptr (n = NG+1)
        int n = NG + 1, nb = (n + 255) / 256;
        k_scan1<<<nb, 256, 0, stream>>>(row_ptr, n, partials);
        k_scan2<<<1, 1024, 0, stream>>>(partials, nb);
        k_scan3<<<nb, 256, 0, stream>>>(row_ptr, n, partials);
    }
    {   // scan col_ptr (n = NU+1)
        int n = NU + 1, nb = (n + 255) / 256;
        k_scan1<<<nb, 256, 0, stream>>>(col_ptr, n, partials);
        k_scan2<<<1, 1024, 0, stream>>>(partials, nb);
        k_scan3<<<nb, 256, 0, stream>>>(col_ptr, n, partials);
    }

    k_initfill<<<1, 512, 0, stream>>>(row_ptr, col_ptr, fillR, fillC);

    // two-pass binned counting sort (replaces the random 8B scatter that
    // cost 8x write amplification / 248MB of HBM writes)
    k_bin<<<(NNZ + 256 * BIN_K - 1) / (256 * BIN_K), 256, 0, stream>>>(
        rows, cols, vals, fillR, fillC, binR, binC, NNZ);
    k_unbin<<<NBR + NBC, 256, 0, stream>>>(row_ptr, col_ptr, binR, binC,
                                           r_edges, c_edges);

    // --- layers (running-sum inits fused into layer-1 epilogues) ---
    for (int l = 0; l < LAYERS; l++) {
        const float* u_in = (l == 0) ? user_emb : U;
        const float* g_in = (l == 0) ? group_emb : M;

        // node_msg = H @ u_in
        k_spmm<<<(NG + 3) / 4, 256, 0, stream>>>(row_ptr, r_edges, u_in,
                                                 node_msg, nullptr, nullptr, NG);

        // M = concat(node_msg, node_msg*g_in) @ W + b ; edge_sum (+)= M
        k_gemm_gate<<<(NG + 63) / 64, 256, 0, stream>>>(
            node_msg, g_in, Ws + (size_t)l * 256 * 128, bs + (size_t)l * 128,
            M, (l == 0) ? group_emb : nullptr, edge_sum, NG);

        // U = H^T @ M ; node_sum (+)= U   (skip dead U store in last layer)
        k_spmm<<<(NU + 3) / 4, 256, 0, stream>>>(col_ptr, c_edges, M,
                                                 (l == LAYERS - 1) ? nullptr : U,
                                                 (l == 0) ? user_emb : nullptr,
                                                 node_sum, NU);
    }
}

// Round 3
// 1831.051 us; speedup vs baseline: 1.1655x; 1.0453x over previous
//
#include <hip/hip_runtime.h>
#include <hip/hip_bf16.h>

#define NG 50000
#define NU 200000
#define DIM 128
#define NNZ 2000000
#define LAYERS 3

// bucket geometry for the binned counting sort
#define RB_SHIFT 7                      // 128 rows per bucket
#define CB_SHIFT 9                      // 512 cols per bucket
#define NBR ((NG + 127) / 128)          // 391
#define NBC ((NU + 511) / 512)          // 391
#define BIN_K 32                        // edges per thread in k_bin (8192/block)

// ---------------- preprocessing: histogram + scan --------------------------

__global__ __launch_bounds__(256) void k_hist(const int* __restrict__ rows,
                                              const int* __restrict__ cols,
                                              int* __restrict__ row_ptr,
                                              int* __restrict__ col_ptr, int nnz) {
    int e = blockIdx.x * 256 + threadIdx.x;
    if (e < nnz) {
        atomicAdd(&row_ptr[rows[e] + 1], 1);
        atomicAdd(&col_ptr[cols[e] + 1], 1);
    }
}

// inclusive scan, 256 per block; partials[b] = block total
__global__ __launch_bounds__(256) void k_scan1(int* __restrict__ a, int n,
                                               int* __restrict__ partials) {
    __shared__ int s[256];
    int t = threadIdx.x;
    int i = blockIdx.x * 256 + t;
    s[t] = (i < n) ? a[i] : 0;
    __syncthreads();
    for (int off = 1; off < 256; off <<= 1) {
        int x = (t >= off) ? s[t - off] : 0;
        __syncthreads();
        s[t] += x;
        __syncthreads();
    }
    if (i < n) a[i] = s[t];
    if (t == 255) partials[blockIdx.x] = s[255];
}

__global__ __launch_bounds__(1024) void k_scan2(int* __restrict__ partials, int nb) {
    __shared__ int s[1024];
    int t = threadIdx.x;
    s[t] = (t < nb) ? partials[t] : 0;
    __syncthreads();
    for (int off = 1; off < 1024; off <<= 1) {
        int x = (t >= off) ? s[t - off] : 0;
        __syncthreads();
        s[t] += x;
        __syncthreads();
    }
    if (t < nb) partials[t] = s[t];
}

__global__ __launch_bounds__(256) void k_scan3(int* __restrict__ a, int n,
                                               const int* __restrict__ partials) {
    int b = blockIdx.x;
    if (b == 0) return;
    int i = b * 256 + threadIdx.x;
    if (i < n) a[i] += partials[b - 1];
}

// seed per-bucket global fill pointers from the CSR/CSC ptr arrays
__global__ __launch_bounds__(512) void k_initfill(const int* __restrict__ row_ptr,
                                                  const int* __restrict__ col_ptr,
                                                  int* __restrict__ fillR,
                                                  int* __restrict__ fillC) {
    int t = threadIdx.x;
    if (t < NBR) fillR[t] = row_ptr[t << RB_SHIFT];
    if (t < NBC) fillC[t] = col_ptr[t << CB_SHIFT];
}

// ---- pass 1: bin edges into bucket-contiguous staging arrays --------------
// binR entry: .x = (local_row<<18)|col  .y = valbits   (7+18 bits, fits)
// binC entry: .x = (local_col<<16)|row  .y = valbits   (9+16 bits, fits)
__global__ __launch_bounds__(256) void k_bin(const int* __restrict__ rows,
                                             const int* __restrict__ cols,
                                             const float* __restrict__ vals,
                                             int* __restrict__ fillR,
                                             int* __restrict__ fillC,
                                             int2* __restrict__ binR,
                                             int2* __restrict__ binC, int nnz) {
    __shared__ int cR[NBR];
    __shared__ int cC[NBC];
    int t = threadIdx.x;
    int base = blockIdx.x * (256 * BIN_K);
    for (int i = t; i < NBR; i += 256) cR[i] = 0;
    for (int i = t; i < NBC; i += 256) cC[i] = 0;
    __syncthreads();
    // count
    for (int k = 0; k < BIN_K; k++) {
        int e = base + k * 256 + t;
        if (e < nnz) {
            atomicAdd(&cR[rows[e] >> RB_SHIFT], 1);
            atomicAdd(&cC[cols[e] >> CB_SHIFT], 1);
        }
    }
    __syncthreads();
    // reserve contiguous runs in the bucket regions; repurpose cR/cC as
    // running global positions
    for (int b = t; b < NBR; b += 256) {
        int n = cR[b];
        cR[b] = n ? atomicAdd(&fillR[b], n) : 0;
    }
    for (int b = t; b < NBC; b += 256) {
        int n = cC[b];
        cC[b] = n ? atomicAdd(&fillC[b], n) : 0;
    }
    __syncthreads();
    // write
    for (int k = 0; k < BIN_K; k++) {
        int e = base + k * 256 + t;
        if (e < nnz) {
            int r = rows[e], c = cols[e];
            int v = __float_as_int(vals[e]);
            int pR = atomicAdd(&cR[r >> RB_SHIFT], 1);
            binR[pR] = make_int2(((r & 127) << 18) | c, v);
            int pC = atomicAdd(&cC[c >> CB_SHIFT], 1);
            binC[pC] = make_int2(((c & 511) << 16) | r, v);
        }
    }
}

// ---- pass 2: within each bucket, scatter to final per-row position --------
// one block per bucket; all writes land inside the bucket's ~40KB region
// which this block fills completely -> full-line writebacks.
__global__ __launch_bounds__(256) void k_unbin(const int* __restrict__ row_ptr,
                                               const int* __restrict__ col_ptr,
                                               const int2* __restrict__ binR,
                                               const int2* __restrict__ binC,
                                               int2* __restrict__ r_edges,
                                               int2* __restrict__ c_edges) {
    __shared__ int pos[512];
    int t = threadIdx.x;
    int b = blockIdx.x;
    if (b < NBR) {
        int r0 = b << RB_SHIFT;
        int nr = min(128, NG - r0);
        if (t < nr) pos[t] = row_ptr[r0 + t];
        __syncthreads();
        int lo = row_ptr[r0];
        int hi = row_ptr[r0 + nr];
        for (int i = lo + t; i < hi; i += 256) {
            int2 e = binR[i];
            int lr = e.x >> 18;
            int c = e.x & 0x3FFFF;
            int p = atomicAdd(&pos[lr], 1);
            r_edges[p] = make_int2(c, e.y);
        }
    } else {
        int c0 = (b - NBR) << CB_SHIFT;
        int nc = min(512, NU - c0);
        for (int i = t; i < nc; i += 256) pos[i] = col_ptr[c0 + i];
        __syncthreads();
        int lo = col_ptr[c0];
        int hi = col_ptr[c0 + nc];
        for (int i = lo + t; i < hi; i += 256) {
            int2 e = binC[i];
            int lc = e.x >> 16;
            int r = e.x & 0xFFFF;
            int p = atomicAdd(&pos[lc], 1);
            c_edges[p] = make_int2(r, e.y);
        }
    }
}

// ---------------- SpMM: one wave per output row, float2 per lane -------------
// out[w] = sum_e val[e] * x[idx[e]]   (edges grouped by w via counting sort)
// optional fused: sum_out[w] = (sum_init ? sum_init[w] : sum_out[w]) + acc

__global__ __launch_bounds__(256) void k_spmm(const int* __restrict__ ptr,
                                              const int2* __restrict__ edges,
                                              const float* __restrict__ x,
                                              float* __restrict__ out,
                                              const float* __restrict__ sum_init,
                                              float* __restrict__ sum_out,
                                              int nrows) {
    int w = blockIdx.x * 4 + (threadIdx.x >> 6);
    int lane = threadIdx.x & 63;
    if (w >= nrows) return;
    int beg = ptr[w], end = ptr[w + 1];
    float a0 = 0.f, a1 = 0.f;
    for (int base = beg; base < end; base += 64) {
        int n = end - base;
        if (n > 64) n = 64;
        int2 e = make_int2(0, 0);
        if (lane < n) e = edges[base + lane];
        int j = 0;
        for (; j + 4 <= n; j += 4) {
            int c0 = __shfl(e.x, j);     float v0 = __int_as_float(__shfl(e.y, j));
            int c1 = __shfl(e.x, j + 1); float v1 = __int_as_float(__shfl(e.y, j + 1));
            int c2 = __shfl(e.x, j + 2); float v2 = __int_as_float(__shfl(e.y, j + 2));
            int c3 = __shfl(e.x, j + 3); float v3 = __int_as_float(__shfl(e.y, j + 3));
            float2 x0 = *((const float2*)(x + (size_t)c0 * DIM) + lane);
            float2 x1 = *((const float2*)(x + (size_t)c1 * DIM) + lane);
            float2 x2 = *((const float2*)(x + (size_t)c2 * DIM) + lane);
            float2 x3 = *((const float2*)(x + (size_t)c3 * DIM) + lane);
            a0 += v0 * x0.x; a1 += v0 * x0.y;
            a0 += v1 * x1.x; a1 += v1 * x1.y;
            a0 += v2 * x2.x; a1 += v2 * x2.y;
            a0 += v3 * x3.x; a1 += v3 * x3.y;
        }
        for (; j < n; j++) {
            int c = __shfl(e.x, j);
            float v = __int_as_float(__shfl(e.y, j));
            float2 xv = *((const float2*)(x + (size_t)c * DIM) + lane);
            a0 += v * xv.x; a1 += v * xv.y;
        }
    }
    size_t o2 = (size_t)w * (DIM / 2) + lane;  // float2 index
    if (out) ((float2*)out)[o2] = make_float2(a0, a1);
    if (sum_out) {
        float2 s;
        if (sum_init) s = ((const float2*)sum_init)[o2];
        else          s = ((const float2*)sum_out)[o2];
        s.x += a0;
        s.y += a1;
        ((float2*)sum_out)[o2] = s;
    }
}

// ---- gated GEMM: msg = concat(nm, nm*grp) @ W + b ;
//      edge_sum = (edge_init ? edge_init : edge_sum) + msg ---------------------
// block = 256 threads, 64 group rows x 128 cols of C per block.
// Register tile 8 rows x 4 cols per thread; all LDS traffic is ds_read_b128:
// per 4-k chunk: 8 X reads (lane-broadcast) + 4 W reads (contiguous) feed
// 128 FMAs -> VALU-bound (the old 32x1 tile issued ~33 ds_read_b32 per 32
// FMAs -> LDS-issue-bound at VALUBusy=34%).
// NOTE: group_cur and msg_out may alias (each block reads only its own rows,
// all reads happen before the epilogue write) -> no __restrict__ on those.

__global__ __launch_bounds__(256) void k_gemm_gate(const float* __restrict__ node_msg,
                                                   const float* group_cur,
                                                   const float* __restrict__ W,
                                                   const float* __restrict__ bias,
                                                   float* msg_out,
                                                   const float* __restrict__ edge_init,
                                                   float* __restrict__ edge_sum, int ng) {
    __shared__ float Ws[64][128];
    __shared__ float Xs[64][64];
    int t = threadIdx.x;
    int tc = t & 31;   // col quad: cols 4*tc .. 4*tc+3
    int tr = t >> 5;   // row octet: rows 8*tr .. 8*tr+7
    int g0 = blockIdx.x * 64;

    float acc[8][4];
#pragma unroll
    for (int r = 0; r < 8; r++)
#pragma unroll
        for (int c = 0; c < 4; c++) acc[r][c] = 0.f;

    for (int kc = 0; kc < 4; kc++) {
        int k0 = kc * 64;
        // stage W chunk: rows [k0, k0+64) x 128 cols, float4 granules
        for (int i = t; i < 64 * 32; i += 256) {
            int row = i >> 5, c4 = (i & 31) << 2;
            *(float4*)&Ws[row][c4] = *(const float4*)&W[(k0 + row) * 128 + c4];
        }
        // stage X chunk: 64 rows x 64 k (gate computed inline), float4 granules
        for (int i = t; i < 64 * 16; i += 256) {
            int r = i >> 4, k4 = (i & 15) << 2;
            int g = g0 + r;
            float4 v = make_float4(0.f, 0.f, 0.f, 0.f);
            if (g < ng) {
                if (k0 < 128) {
                    v = *(const float4*)&node_msg[g * 128 + k0 + k4];
                } else {
                    float4 a = *(const float4*)&node_msg[g * 128 + (k0 - 128) + k4];
                    float4 b = *(const float4*)(group_cur + g * 128 + (k0 - 128) + k4);
                    v = make_float4(a.x * b.x, a.y * b.y, a.z * b.z, a.w * b.w);
                }
            }
            *(float4*)&Xs[r][k4] = v;
        }
        __syncthreads();
#pragma unroll
        for (int kq = 0; kq < 16; kq++) {
            float4 w0 = *(float4*)&Ws[kq * 4 + 0][tc * 4];
            float4 w1 = *(float4*)&Ws[kq * 4 + 1][tc * 4];
            float4 w2 = *(float4*)&Ws[kq * 4 + 2][tc * 4];
            float4 w3 = *(float4*)&Ws[kq * 4 + 3][tc * 4];
#pragma unroll
            for (int ri = 0; ri < 8; ri++) {
                float4 xv = *(float4*)&Xs[tr * 8 + ri][kq * 4];
                acc[ri][0] += xv.x * w0.x + xv.y * w1.x + xv.z * w2.x + xv.w * w3.x;
                acc[ri][1] += xv.x * w0.y + xv.y * w1.y + xv.z * w2.y + xv.w * w3.y;
                acc[ri][2] += xv.x * w0.z + xv.y * w1.z + xv.z * w2.z + xv.w * w3.z;
                acc[ri][3] += xv.x * w0.w + xv.y * w1.w + xv.z * w2.w + xv.w * w3.w;
            }
        }
        __syncthreads();
    }

    float4 b4 = *(const float4*)&bias[tc * 4];
#pragma unroll
    for (int ri = 0; ri < 8; ri++) {
        int g = g0 + tr * 8 + ri;
        if (g < ng) {
            size_t idx = (size_t)g * 128 + tc * 4;
            float4 v = make_float4(acc[ri][0] + b4.x, acc[ri][1] + b4.y,
                                   acc[ri][2] + b4.z, acc[ri][3] + b4.w);
            float4 es = edge_init ? *(const float4*)&edge_init[idx]
                                  : *(const float4*)&edge_sum[idx];
            *(float4*)(msg_out + idx) = v;
            es.x += v.x; es.y += v.y; es.z += v.z; es.w += v.w;
            *(float4*)&edge_sum[idx] = es;
        }
    }
}

// ---------------------------------------------------------------------------

extern "C" void kernel_launch(void* const* d_in, const int* in_sizes, int n_in,
                              void* d_out, int out_size, void* d_ws, size_t ws_size,
                              hipStream_t stream) {
    const float* group_emb = (const float*)d_in[0];  // [NG,128]
    const float* user_emb  = (const float*)d_in[1];  // [NU,128]
    const int*   rows      = (const int*)d_in[2];    // [NNZ]
    const int*   cols      = (const int*)d_in[3];    // [NNZ]
    const float* vals      = (const float*)d_in[4];  // [NNZ]
    const float* Ws        = (const float*)d_in[5];  // [3,256,128]
    const float* bs        = (const float*)d_in[6];  // [3,128]

    float* node_sum = (float*)d_out;                 // [NU,128]
    float* edge_sum = (float*)d_out + (size_t)NU * DIM;  // [NG,128]

    // workspace carve (16B aligned)
    char* p = (char*)d_ws;
    auto carve = [&](size_t bytes) {
        void* r = (void*)p;
        p += (bytes + 15) & ~(size_t)15;
        return r;
    };
    float* U        = (float*)carve((size_t)NU * DIM * 4);   // user ping buffer
    float* M        = (float*)carve((size_t)NG * DIM * 4);   // msg buffer
    float* node_msg = (float*)carve((size_t)NG * DIM * 4);
    int*   row_ptr  = (int*)carve((NG + 1) * 4);
    int*   col_ptr  = (int*)carve((NU + 1) * 4);
    int*   fillR    = (int*)carve(NBR * 4);
    int*   fillC    = (int*)carve(NBC * 4);
    int2*  r_edges  = (int2*)carve((size_t)NNZ * 8);
    int2*  c_edges  = (int2*)carve((size_t)NNZ * 8);
    int*   partials = (int*)carve(1024 * 4);

    // binned staging buffers alias U: U is not live until the first layer,
    // and preprocessing finishes before the layers start. 2*NNZ*8 = 32MB
    // fits comfortably inside U's 102.4MB.
    int2* binR = (int2*)U;
    int2* binC = binR + NNZ;

    // --- build CSR (row-sorted) and CSC (col-sorted) packed edge lists ---
    hipMemsetAsync(row_ptr, 0, (NG + 1) * 4, stream);
    hipMemsetAsync(col_ptr, 0, (NU + 1) * 4, stream);

    k_hist<<<(NNZ + 255) / 256, 256, 0, stream>>>(rows, cols, row_ptr, col_ptr, NNZ);

    {   // scan row_ptr (n = NG+1)
        int n = NG + 1, nb = (n + 255) / 256;
        k_scan1<<<nb, 256, 0, stream>>>(row_ptr, n, partials);
        k_scan2<<<1, 1024, 0, stream>>>(partials, nb);
        k_scan3<<<nb, 256, 0, stream>>>(row_ptr, n, partials);
    }
    {   // scan col_ptr (n = NU+1)
        int n = NU + 1, nb = (n + 255) / 256;
        k_scan1<<<nb, 256, 0, stream>>>(col_ptr, n, partials);
        k_scan2<<<1, 1024, 0, stream>>>(partials, nb);
        k_scan3<<<nb, 256, 0, stream>>>(col_ptr, n, partials);
    }

    k_initfill<<<1, 512, 0, stream>>>(row_ptr, col_ptr, fillR, fillC);

    // two-pass binned counting sort (replaces the random 8B scatter that
    // cost 8x write amplification / 248MB of HBM writes)
    k_bin<<<(NNZ + 256 * BIN_K - 1) / (256 * BIN_K), 256, 0, stream>>>(
        rows, cols, vals, fillR, fillC, binR, binC, NNZ);
    k_unbin<<<NBR + NBC, 256, 0, stream>>>(row_ptr, col_ptr, binR, binC,
                                           r_edges, c_edges);

    // --- layers (running-sum inits fused into layer-1 epilogues) ---
    for (int l = 0; l < LAYERS; l++) {
        const float* u_in = (l == 0) ? user_emb : U;
        const float* g_in = (l == 0) ? group_emb : M;

        // node_msg = H @ u_in
        k_spmm<<<(NG + 3) / 4, 256, 0, stream>>>(row_ptr, r_edges, u_in,
                                                 node_msg, nullptr, nullptr, NG);

        // M = concat(node_msg, node_msg*g_in) @ W + b ; edge_sum (+)= M
        k_gemm_gate<<<(NG + 63) / 64, 256, 0, stream>>>(
            node_msg, g_in, Ws + (size_t)l * 256 * 128, bs + (size_t)l * 128,
            M, (l == 0) ? group_emb : nullptr, edge_sum, NG);

        // U = H^T @ M ; node_sum (+)= U   (skip dead U store in last layer)
        k_spmm<<<(NU + 3) / 4, 256, 0, stream>>>(col_ptr, c_edges, M,
                                                 (l == LAYERS - 1) ? nullptr : U,
                                                 (l == 0) ? user_emb : nullptr,
                                                 node_sum, NU);
    }
}

// Round 4
// 1812.335 us; speedup vs baseline: 1.1775x; 1.0103x over previous
//
#include <hip/hip_runtime.h>
#include <hip/hip_bf16.h>

#define NG 50000
#define NU 200000
#define DIM 128
#define NNZ 2000000
#define LAYERS 3

// bucket geometry for the binned counting sort
#define RB_SHIFT 7                      // 128 rows per bucket
#define CB_SHIFT 9                      // 512 cols per bucket
#define NBR ((NG + 127) / 128)          // 391
#define NBC ((NU + 511) / 512)          // 391
#define BIN_K 32                        // edges per thread in k_bin (8192/block)

// native vector types for nontemporal builtins (struct float2/float4 are not
// accepted by __builtin_nontemporal_load/store; ext_vector types are)
typedef float v2f __attribute__((ext_vector_type(2)));
typedef float v4f __attribute__((ext_vector_type(4)));

// ---------------- preprocessing: histogram + scan --------------------------

__global__ __launch_bounds__(256) void k_hist(const int* __restrict__ rows,
                                              const int* __restrict__ cols,
                                              int* __restrict__ row_ptr,
                                              int* __restrict__ col_ptr, int nnz) {
    int e = blockIdx.x * 256 + threadIdx.x;
    if (e < nnz) {
        atomicAdd(&row_ptr[rows[e] + 1], 1);
        atomicAdd(&col_ptr[cols[e] + 1], 1);
    }
}

// inclusive scan, 256 per block; partials[b] = block total
__global__ __launch_bounds__(256) void k_scan1(int* __restrict__ a, int n,
                                               int* __restrict__ partials) {
    __shared__ int s[256];
    int t = threadIdx.x;
    int i = blockIdx.x * 256 + t;
    s[t] = (i < n) ? a[i] : 0;
    __syncthreads();
    for (int off = 1; off < 256; off <<= 1) {
        int x = (t >= off) ? s[t - off] : 0;
        __syncthreads();
        s[t] += x;
        __syncthreads();
    }
    if (i < n) a[i] = s[t];
    if (t == 255) partials[blockIdx.x] = s[255];
}

__global__ __launch_bounds__(1024) void k_scan2(int* __restrict__ partials, int nb) {
    __shared__ int s[1024];
    int t = threadIdx.x;
    s[t] = (t < nb) ? partials[t] : 0;
    __syncthreads();
    for (int off = 1; off < 1024; off <<= 1) {
        int x = (t >= off) ? s[t - off] : 0;
        __syncthreads();
        s[t] += x;
        __syncthreads();
    }
    if (t < nb) partials[t] = s[t];
}

__global__ __launch_bounds__(256) void k_scan3(int* __restrict__ a, int n,
                                               const int* __restrict__ partials) {
    int b = blockIdx.x;
    if (b == 0) return;
    int i = b * 256 + threadIdx.x;
    if (i < n) a[i] += partials[b - 1];
}

// seed per-bucket global fill pointers from the CSR/CSC ptr arrays
__global__ __launch_bounds__(512) void k_initfill(const int* __restrict__ row_ptr,
                                                  const int* __restrict__ col_ptr,
                                                  int* __restrict__ fillR,
                                                  int* __restrict__ fillC) {
    int t = threadIdx.x;
    if (t < NBR) fillR[t] = row_ptr[t << RB_SHIFT];
    if (t < NBC) fillC[t] = col_ptr[t << CB_SHIFT];
}

// ---- pass 1: bin edges into bucket-contiguous staging arrays --------------
// binR entry: .x = (local_row<<18)|col  .y = valbits   (7+18 bits, fits)
// binC entry: .x = (local_col<<16)|row  .y = valbits   (9+16 bits, fits)
__global__ __launch_bounds__(256) void k_bin(const int* __restrict__ rows,
                                             const int* __restrict__ cols,
                                             const float* __restrict__ vals,
                                             int* __restrict__ fillR,
                                             int* __restrict__ fillC,
                                             int2* __restrict__ binR,
                                             int2* __restrict__ binC, int nnz) {
    __shared__ int cR[NBR];
    __shared__ int cC[NBC];
    int t = threadIdx.x;
    int base = blockIdx.x * (256 * BIN_K);
    for (int i = t; i < NBR; i += 256) cR[i] = 0;
    for (int i = t; i < NBC; i += 256) cC[i] = 0;
    __syncthreads();
    // count
    for (int k = 0; k < BIN_K; k++) {
        int e = base + k * 256 + t;
        if (e < nnz) {
            atomicAdd(&cR[rows[e] >> RB_SHIFT], 1);
            atomicAdd(&cC[cols[e] >> CB_SHIFT], 1);
        }
    }
    __syncthreads();
    // reserve contiguous runs in the bucket regions; repurpose cR/cC as
    // running global positions
    for (int b = t; b < NBR; b += 256) {
        int n = cR[b];
        cR[b] = n ? atomicAdd(&fillR[b], n) : 0;
    }
    for (int b = t; b < NBC; b += 256) {
        int n = cC[b];
        cC[b] = n ? atomicAdd(&fillC[b], n) : 0;
    }
    __syncthreads();
    // write
    for (int k = 0; k < BIN_K; k++) {
        int e = base + k * 256 + t;
        if (e < nnz) {
            int r = rows[e], c = cols[e];
            int v = __float_as_int(vals[e]);
            int pR = atomicAdd(&cR[r >> RB_SHIFT], 1);
            binR[pR] = make_int2(((r & 127) << 18) | c, v);
            int pC = atomicAdd(&cC[c >> CB_SHIFT], 1);
            binC[pC] = make_int2(((c & 511) << 16) | r, v);
        }
    }
}

// ---- pass 2: within each bucket, scatter to final per-row position --------
// one block per bucket; all writes land inside the bucket's ~40KB region
// which this block fills completely -> full-line writebacks.
__global__ __launch_bounds__(256) void k_unbin(const int* __restrict__ row_ptr,
                                               const int* __restrict__ col_ptr,
                                               const int2* __restrict__ binR,
                                               const int2* __restrict__ binC,
                                               int2* __restrict__ r_edges,
                                               int2* __restrict__ c_edges) {
    __shared__ int pos[512];
    int t = threadIdx.x;
    int b = blockIdx.x;
    if (b < NBR) {
        int r0 = b << RB_SHIFT;
        int nr = min(128, NG - r0);
        if (t < nr) pos[t] = row_ptr[r0 + t];
        __syncthreads();
        int lo = row_ptr[r0];
        int hi = row_ptr[r0 + nr];
        for (int i = lo + t; i < hi; i += 256) {
            int2 e = binR[i];
            int lr = e.x >> 18;
            int c = e.x & 0x3FFFF;
            int p = atomicAdd(&pos[lr], 1);
            r_edges[p] = make_int2(c, e.y);
        }
    } else {
        int c0 = (b - NBR) << CB_SHIFT;
        int nc = min(512, NU - c0);
        for (int i = t; i < nc; i += 256) pos[i] = col_ptr[c0 + i];
        __syncthreads();
        int lo = col_ptr[c0];
        int hi = col_ptr[c0 + nc];
        for (int i = lo + t; i < hi; i += 256) {
            int2 e = binC[i];
            int lc = e.x >> 16;
            int r = e.x & 0xFFFF;
            int p = atomicAdd(&pos[lc], 1);
            c_edges[p] = make_int2(r, e.y);
        }
    }
}

// ---------------- SpMM: one wave per output row, float2 per lane -------------
// out[w] = sum_e val[e] * x[idx[e]]   (edges grouped by w via counting sort)
// optional fused: sum_out[w] = (sum_init ? sum_init[w] : sum_out[w]) + acc
//
// Cache policy: the gather source x has 10-40x reuse and must stay resident
// in the 256MB Infinity Cache; the sum stream (read-once/write-once, up to
// 300MB per dispatch) was evicting it (FETCH_SIZE 504MB vs ~150MB ideal).
// -> sum_init/sum_out use nontemporal hints; x gathers and the `out` store
// (which is the NEXT kernel's gather source) stay normally cached.

__global__ __launch_bounds__(256) void k_spmm(const int* __restrict__ ptr,
                                              const int2* __restrict__ edges,
                                              const float* __restrict__ x,
                                              float* __restrict__ out,
                                              const float* __restrict__ sum_init,
                                              float* __restrict__ sum_out,
                                              int nrows) {
    int w = blockIdx.x * 4 + (threadIdx.x >> 6);
    int lane = threadIdx.x & 63;
    if (w >= nrows) return;
    int beg = ptr[w], end = ptr[w + 1];
    float a0 = 0.f, a1 = 0.f;
    for (int base = beg; base < end; base += 64) {
        int n = end - base;
        if (n > 64) n = 64;
        int2 e = make_int2(0, 0);
        if (lane < n) e = edges[base + lane];
        int j = 0;
        for (; j + 4 <= n; j += 4) {
            int c0 = __shfl(e.x, j);     float v0 = __int_as_float(__shfl(e.y, j));
            int c1 = __shfl(e.x, j + 1); float v1 = __int_as_float(__shfl(e.y, j + 1));
            int c2 = __shfl(e.x, j + 2); float v2 = __int_as_float(__shfl(e.y, j + 2));
            int c3 = __shfl(e.x, j + 3); float v3 = __int_as_float(__shfl(e.y, j + 3));
            float2 x0 = *((const float2*)(x + (size_t)c0 * DIM) + lane);
            float2 x1 = *((const float2*)(x + (size_t)c1 * DIM) + lane);
            float2 x2 = *((const float2*)(x + (size_t)c2 * DIM) + lane);
            float2 x3 = *((const float2*)(x + (size_t)c3 * DIM) + lane);
            a0 += v0 * x0.x; a1 += v0 * x0.y;
            a0 += v1 * x1.x; a1 += v1 * x1.y;
            a0 += v2 * x2.x; a1 += v2 * x2.y;
            a0 += v3 * x3.x; a1 += v3 * x3.y;
        }
        for (; j < n; j++) {
            int c = __shfl(e.x, j);
            float v = __int_as_float(__shfl(e.y, j));
            float2 xv = *((const float2*)(x + (size_t)c * DIM) + lane);
            a0 += v * xv.x; a1 += v * xv.y;
        }
    }
    size_t o2 = (size_t)w * (DIM / 2) + lane;  // float2 index
    if (out) ((float2*)out)[o2] = make_float2(a0, a1);  // normal: reused next kernel
    if (sum_out) {
        v2f s;
        if (sum_init) s = __builtin_nontemporal_load((const v2f*)sum_init + o2);
        else          s = __builtin_nontemporal_load((const v2f*)sum_out + o2);
        s.x += a0;
        s.y += a1;
        __builtin_nontemporal_store(s, (v2f*)sum_out + o2);
    }
}

// ---- gated GEMM: msg = concat(nm, nm*grp) @ W + b ;
//      edge_sum = (edge_init ? edge_init : edge_sum) + msg ---------------------
// block = 256 threads, 64 group rows x 128 cols of C per block.
// Register tile 8 rows x 4 cols per thread; all LDS traffic is ds_read_b128.
// edge_sum RMW stream is nontemporal (pure stream, never re-read with reuse);
// msg_out (= M, the next spmm's gather source) stays normally cached.
// NOTE: group_cur and msg_out may alias (each block reads only its own rows,
// all reads happen before the epilogue write) -> no __restrict__ on those.

__global__ __launch_bounds__(256) void k_gemm_gate(const float* __restrict__ node_msg,
                                                   const float* group_cur,
                                                   const float* __restrict__ W,
                                                   const float* __restrict__ bias,
                                                   float* msg_out,
                                                   const float* __restrict__ edge_init,
                                                   float* __restrict__ edge_sum, int ng) {
    __shared__ float Ws[64][128];
    __shared__ float Xs[64][64];
    int t = threadIdx.x;
    int tc = t & 31;   // col quad: cols 4*tc .. 4*tc+3
    int tr = t >> 5;   // row octet: rows 8*tr .. 8*tr+7
    int g0 = blockIdx.x * 64;

    float acc[8][4];
#pragma unroll
    for (int r = 0; r < 8; r++)
#pragma unroll
        for (int c = 0; c < 4; c++) acc[r][c] = 0.f;

    for (int kc = 0; kc < 4; kc++) {
        int k0 = kc * 64;
        // stage W chunk: rows [k0, k0+64) x 128 cols, float4 granules
        for (int i = t; i < 64 * 32; i += 256) {
            int row = i >> 5, c4 = (i & 31) << 2;
            *(float4*)&Ws[row][c4] = *(const float4*)&W[(k0 + row) * 128 + c4];
        }
        // stage X chunk: 64 rows x 64 k (gate computed inline), float4 granules
        for (int i = t; i < 64 * 16; i += 256) {
            int r = i >> 4, k4 = (i & 15) << 2;
            int g = g0 + r;
            float4 v = make_float4(0.f, 0.f, 0.f, 0.f);
            if (g < ng) {
                if (k0 < 128) {
                    v = *(const float4*)&node_msg[g * 128 + k0 + k4];
                } else {
                    float4 a = *(const float4*)&node_msg[g * 128 + (k0 - 128) + k4];
                    float4 b = *(const float4*)(group_cur + g * 128 + (k0 - 128) + k4);
                    v = make_float4(a.x * b.x, a.y * b.y, a.z * b.z, a.w * b.w);
                }
            }
            *(float4*)&Xs[r][k4] = v;
        }
        __syncthreads();
#pragma unroll
        for (int kq = 0; kq < 16; kq++) {
            float4 w0 = *(float4*)&Ws[kq * 4 + 0][tc * 4];
            float4 w1 = *(float4*)&Ws[kq * 4 + 1][tc * 4];
            float4 w2 = *(float4*)&Ws[kq * 4 + 2][tc * 4];
            float4 w3 = *(float4*)&Ws[kq * 4 + 3][tc * 4];
#pragma unroll
            for (int ri = 0; ri < 8; ri++) {
                float4 xv = *(float4*)&Xs[tr * 8 + ri][kq * 4];
                acc[ri][0] += xv.x * w0.x + xv.y * w1.x + xv.z * w2.x + xv.w * w3.x;
                acc[ri][1] += xv.x * w0.y + xv.y * w1.y + xv.z * w2.y + xv.w * w3.y;
                acc[ri][2] += xv.x * w0.z + xv.y * w1.z + xv.z * w2.z + xv.w * w3.z;
                acc[ri][3] += xv.x * w0.w + xv.y * w1.w + xv.z * w2.w + xv.w * w3.w;
            }
        }
        __syncthreads();
    }

    float4 b4 = *(const float4*)&bias[tc * 4];
#pragma unroll
    for (int ri = 0; ri < 8; ri++) {
        int g = g0 + tr * 8 + ri;
        if (g < ng) {
            size_t idx = (size_t)g * 128 + tc * 4;
            v4f v;
            v.x = acc[ri][0] + b4.x; v.y = acc[ri][1] + b4.y;
            v.z = acc[ri][2] + b4.z; v.w = acc[ri][3] + b4.w;
            v4f es = edge_init
                ? __builtin_nontemporal_load((const v4f*)(edge_init + idx))
                : __builtin_nontemporal_load((const v4f*)(edge_sum + idx));
            *(v4f*)(msg_out + idx) = v;  // normal: gather source of next spmm
            __builtin_nontemporal_store(es + v, (v4f*)(edge_sum + idx));
        }
    }
}

// ---------------------------------------------------------------------------

extern "C" void kernel_launch(void* const* d_in, const int* in_sizes, int n_in,
                              void* d_out, int out_size, void* d_ws, size_t ws_size,
                              hipStream_t stream) {
    const float* group_emb = (const float*)d_in[0];  // [NG,128]
    const float* user_emb  = (const float*)d_in[1];  // [NU,128]
    const int*   rows      = (const int*)d_in[2];    // [NNZ]
    const int*   cols      = (const int*)d_in[3];    // [NNZ]
    const float* vals      = (const float*)d_in[4];  // [NNZ]
    const float* Ws        = (const float*)d_in[5];  // [3,256,128]
    const float* bs        = (const float*)d_in[6];  // [3,128]

    float* node_sum = (float*)d_out;                 // [NU,128]
    float* edge_sum = (float*)d_out + (size_t)NU * DIM;  // [NG,128]

    // workspace carve (16B aligned)
    char* p = (char*)d_ws;
    auto carve = [&](size_t bytes) {
        void* r = (void*)p;
        p += (bytes + 15) & ~(size_t)15;
        return r;
    };
    float* U        = (float*)carve((size_t)NU * DIM * 4);   // user ping buffer
    float* M        = (float*)carve((size_t)NG * DIM * 4);   // msg buffer
    float* node_msg = (float*)carve((size_t)NG * DIM * 4);
    int*   row_ptr  = (int*)carve((NG + 1) * 4);
    int*   col_ptr  = (int*)carve((NU + 1) * 4);
    int*   fillR    = (int*)carve(NBR * 4);
    int*   fillC    = (int*)carve(NBC * 4);
    int2*  r_edges  = (int2*)carve((size_t)NNZ * 8);
    int2*  c_edges  = (int2*)carve((size_t)NNZ * 8);
    int*   partials = (int*)carve(1024 * 4);

    // binned staging buffers alias U: U is not live until the first layer,
    // and preprocessing finishes before the layers start. 2*NNZ*8 = 32MB
    // fits comfortably inside U's 102.4MB.
    int2* binR = (int2*)U;
    int2* binC = binR + NNZ;

    // --- build CSR (row-sorted) and CSC (col-sorted) packed edge lists ---
    hipMemsetAsync(row_ptr, 0, (NG + 1) * 4, stream);
    hipMemsetAsync(col_ptr, 0, (NU + 1) * 4, stream);

    k_hist<<<(NNZ + 255) / 256, 256, 0, stream>>>(rows, cols, row_ptr, col_ptr, NNZ);

    {   // scan row_ptr (n = NG+1)
        int n = NG + 1, nb = (n + 255) / 256;
        k_scan1<<<nb, 256, 0, stream>>>(row_ptr, n, partials);
        k_scan2<<<1, 1024, 0, stream>>>(partials, nb);
        k_scan3<<<nb, 256, 0, stream>>>(row_ptr, n, partials);
    }
    {   // scan col_ptr (n = NU+1)
        int n = NU + 1, nb = (n + 255) / 256;
        k_scan1<<<nb, 256, 0, stream>>>(col_ptr, n, partials);
        k_scan2<<<1, 1024, 0, stream>>>(partials, nb);
        k_scan3<<<nb, 256, 0, stream>>>(col_ptr, n, partials);
    }

    k_initfill<<<1, 512, 0, stream>>>(row_ptr, col_ptr, fillR, fillC);

    // two-pass binned counting sort (replaces the random 8B scatter that
    // cost 8x write amplification / 248MB of HBM writes)
    k_bin<<<(NNZ + 256 * BIN_K - 1) / (256 * BIN_K), 256, 0, stream>>>(
        rows, cols, vals, fillR, fillC, binR, binC, NNZ);
    k_unbin<<<NBR + NBC, 256, 0, stream>>>(row_ptr, col_ptr, binR, binC,
                                           r_edges, c_edges);

    // --- layers (running-sum inits fused into layer-1 epilogues) ---
    for (int l = 0; l < LAYERS; l++) {
        const float* u_in = (l == 0) ? user_emb : U;
        const float* g_in = (l == 0) ? group_emb : M;

        // node_msg = H @ u_in
        k_spmm<<<(NG + 3) / 4, 256, 0, stream>>>(row_ptr, r_edges, u_in,
                                                 node_msg, nullptr, nullptr, NG);

        // M = concat(node_msg, node_msg*g_in) @ W + b ; edge_sum (+)= M
        k_gemm_gate<<<(NG + 63) / 64, 256, 0, stream>>>(
            node_msg, g_in, Ws + (size_t)l * 256 * 128, bs + (size_t)l * 128,
            M, (l == 0) ? group_emb : nullptr, edge_sum, NG);

        // U = H^T @ M ; node_sum (+)= U   (skip dead U store in last layer)
        k_spmm<<<(NU + 3) / 4, 256, 0, stream>>>(col_ptr, c_edges, M,
                                                 (l == LAYERS - 1) ? nullptr : U,
                                                 (l == 0) ? user_emb : nullptr,
                                                 node_sum, NU);
    }
}

// Round 5
// 1448.233 us; speedup vs baseline: 1.4735x; 1.2514x over previous
//
#include <hip/hip_runtime.h>
#include <hip/hip_bf16.h>

#define NG 50000
#define NU 200000
#define DIM 128
#define NNZ 2000000
#define LAYERS 3

// bucket geometry for the binned counting sort
#define RB_SHIFT 7                      // 128 rows per bucket
#define CB_SHIFT 9                      // 512 cols per bucket
#define NBR ((NG + 127) / 128)          // 391
#define NBC ((NU + 511) / 512)          // 391
#define BIN_K 32                        // edges per thread in k_bin (8192/block)

// native vector types for nontemporal builtins
typedef float v2f __attribute__((ext_vector_type(2)));
typedef float v4f __attribute__((ext_vector_type(4)));

// ---- coarse bucket histogram: LDS-aggregated, replaces the 161us k_hist ----
// (the old per-row global-atomic hist wrote 124MB of bounced 64B lines; the
// exact per-row offsets are now computed inside k_unbin from LDS histograms)

__global__ __launch_bounds__(256) void k_hist_coarse(const int* __restrict__ rows,
                                                     const int* __restrict__ cols,
                                                     int* __restrict__ bktcnt, int nnz) {
    __shared__ int cR[NBR];
    __shared__ int cC[NBC];
    int t = threadIdx.x;
    for (int i = t; i < NBR; i += 256) cR[i] = 0;
    for (int i = t; i < NBC; i += 256) cC[i] = 0;
    __syncthreads();
    int stride = gridDim.x * 256;
    for (int e = blockIdx.x * 256 + t; e < nnz; e += stride) {
        atomicAdd(&cR[rows[e] >> RB_SHIFT], 1);
        atomicAdd(&cC[cols[e] >> CB_SHIFT], 1);
    }
    __syncthreads();
    for (int i = t; i < NBR; i += 256) if (cR[i]) atomicAdd(&bktcnt[i], cR[i]);
    for (int i = t; i < NBC; i += 256) if (cC[i]) atomicAdd(&bktcnt[NBR + i], cC[i]);
}

// single-block scan of the 782 bucket counts -> bucket bases + k_bin seeds
__global__ __launch_bounds__(1024) void k_scanb(const int* __restrict__ bktcnt,
                                                int* __restrict__ baseR,
                                                int* __restrict__ baseC,
                                                int* __restrict__ fillR,
                                                int* __restrict__ fillC) {
    __shared__ int s[1024];
    int t = threadIdx.x;
    const int n = NBR + NBC;
    s[t] = (t < n) ? bktcnt[t] : 0;
    __syncthreads();
    for (int off = 1; off < 1024; off <<= 1) {
        int x = (t >= off) ? s[t - off] : 0;
        __syncthreads();
        s[t] += x;
        __syncthreads();
    }
    int excl = (t == 0) ? 0 : s[t - 1];
    if (t < NBR) { baseR[t] = excl; fillR[t] = excl; }
    else if (t < n) { int v = excl - NNZ; baseC[t - NBR] = v; fillC[t - NBR] = v; }
    if (t == 0) { baseR[NBR] = NNZ; baseC[NBC] = NNZ; }
}

// ---- pass 1: bin edges into bucket-contiguous staging arrays --------------
// binR entry: .x = (local_row<<18)|col  .y = valbits   (7+18 bits, fits)
// binC entry: .x = (local_col<<16)|row  .y = valbits   (9+16 bits, fits)
__global__ __launch_bounds__(256) void k_bin(const int* __restrict__ rows,
                                             const int* __restrict__ cols,
                                             const float* __restrict__ vals,
                                             int* __restrict__ fillR,
                                             int* __restrict__ fillC,
                                             int2* __restrict__ binR,
                                             int2* __restrict__ binC, int nnz) {
    __shared__ int cR[NBR];
    __shared__ int cC[NBC];
    int t = threadIdx.x;
    int base = blockIdx.x * (256 * BIN_K);
    for (int i = t; i < NBR; i += 256) cR[i] = 0;
    for (int i = t; i < NBC; i += 256) cC[i] = 0;
    __syncthreads();
    // count
    for (int k = 0; k < BIN_K; k++) {
        int e = base + k * 256 + t;
        if (e < nnz) {
            atomicAdd(&cR[rows[e] >> RB_SHIFT], 1);
            atomicAdd(&cC[cols[e] >> CB_SHIFT], 1);
        }
    }
    __syncthreads();
    // reserve contiguous runs in the bucket regions; repurpose cR/cC as
    // running global positions
    for (int b = t; b < NBR; b += 256) {
        int n = cR[b];
        cR[b] = n ? atomicAdd(&fillR[b], n) : 0;
    }
    for (int b = t; b < NBC; b += 256) {
        int n = cC[b];
        cC[b] = n ? atomicAdd(&fillC[b], n) : 0;
    }
    __syncthreads();
    // write
    for (int k = 0; k < BIN_K; k++) {
        int e = base + k * 256 + t;
        if (e < nnz) {
            int r = rows[e], c = cols[e];
            int v = __float_as_int(vals[e]);
            int pR = atomicAdd(&cR[r >> RB_SHIFT], 1);
            binR[pR] = make_int2(((r & 127) << 18) | c, v);
            int pC = atomicAdd(&cC[c >> CB_SHIFT], 1);
            binC[pC] = make_int2(((c & 511) << 16) | r, v);
        }
    }
}

// ---- pass 2: per bucket: LDS hist -> wave scan -> write row_ptr/col_ptr ----
// -> scatter to final per-row position. All traffic stays in the bucket's
// ~40KB region (L2-hot), writes are full-line.
__global__ __launch_bounds__(256) void k_unbin(const int* __restrict__ baseR,
                                               const int* __restrict__ baseC,
                                               const int2* __restrict__ binR,
                                               const int2* __restrict__ binC,
                                               int* __restrict__ row_ptr,
                                               int* __restrict__ col_ptr,
                                               int2* __restrict__ r_edges,
                                               int2* __restrict__ c_edges) {
    __shared__ int pos[512];
    int t = threadIdx.x;
    int b = blockIdx.x;
    if (b < NBR) {
        int r0 = b << RB_SHIFT;
        int nr = min(128, NG - r0);
        int lo = baseR[b], hi = baseR[b + 1];
        if (t < 128) pos[t] = 0;
        __syncthreads();
        for (int i = lo + t; i < hi; i += 256)
            atomicAdd(&pos[binR[i].x >> 18], 1);
        __syncthreads();
        if (t < 64) {  // wave 0: exclusive scan of 128 counters, 2 per lane
            int lane = t;
            int i0 = lane * 2;
            int n0 = pos[i0], n1 = pos[i0 + 1];
            int s = n0 + n1;
            int v = s;
#pragma unroll
            for (int off = 1; off < 64; off <<= 1) {
                int u = __shfl_up(v, off);
                if (lane >= off) v += u;
            }
            int run = lo + (v - s);
            if (i0 < nr) row_ptr[r0 + i0] = run;
            pos[i0] = run; run += n0;
            if (i0 + 1 < nr) row_ptr[r0 + i0 + 1] = run;
            pos[i0 + 1] = run;
        }
        if (b == NBR - 1 && t == 0) row_ptr[NG] = NNZ;
        __syncthreads();
        for (int i = lo + t; i < hi; i += 256) {
            int2 e = binR[i];
            int lr = e.x >> 18;
            int c = e.x & 0x3FFFF;
            int p = atomicAdd(&pos[lr], 1);
            r_edges[p] = make_int2(c, e.y);
        }
    } else {
        int cb = b - NBR;
        int c0 = cb << CB_SHIFT;
        int nc = min(512, NU - c0);
        int lo = baseC[cb], hi = baseC[cb + 1];
        for (int i = t; i < 512; i += 256) pos[i] = 0;
        __syncthreads();
        for (int i = lo + t; i < hi; i += 256)
            atomicAdd(&pos[binC[i].x >> 16], 1);
        __syncthreads();
        if (t < 64) {  // wave 0: exclusive scan of 512 counters, 8 per lane
            int lane = t;
            int i0 = lane * 8;
            int n[8];
            int s = 0;
#pragma unroll
            for (int j = 0; j < 8; j++) { n[j] = pos[i0 + j]; s += n[j]; }
            int v = s;
#pragma unroll
            for (int off = 1; off < 64; off <<= 1) {
                int u = __shfl_up(v, off);
                if (lane >= off) v += u;
            }
            int run = lo + (v - s);
#pragma unroll
            for (int j = 0; j < 8; j++) {
                if (i0 + j < nc) col_ptr[c0 + i0 + j] = run;
                pos[i0 + j] = run;
                run += n[j];
            }
        }
        if (b == NBR + NBC - 1 && t == 0) col_ptr[NU] = NNZ;
        __syncthreads();
        for (int i = lo + t; i < hi; i += 256) {
            int2 e = binC[i];
            int lc = e.x >> 16;
            int r = e.x & 0xFFFF;
            int p = atomicAdd(&pos[lc], 1);
            c_edges[p] = make_int2(r, e.y);
        }
    }
}

// ---------------- SpMM: one wave per output row, float2 per lane -------------
// out[w] = sum_e val[e] * x[idx[e]]   (edges grouped by w via counting sort)
// optional fused: sum_out[w] = (sum_init ? sum_init[w] : sum_out[w]) + acc

__global__ __launch_bounds__(256) void k_spmm(const int* __restrict__ ptr,
                                              const int2* __restrict__ edges,
                                              const float* __restrict__ x,
                                              float* __restrict__ out,
                                              const float* __restrict__ sum_init,
                                              float* __restrict__ sum_out,
                                              int nrows) {
    int w = blockIdx.x * 4 + (threadIdx.x >> 6);
    int lane = threadIdx.x & 63;
    if (w >= nrows) return;
    int beg = ptr[w], end = ptr[w + 1];
    float a0 = 0.f, a1 = 0.f;
    for (int base = beg; base < end; base += 64) {
        int n = end - base;
        if (n > 64) n = 64;
        int2 e = make_int2(0, 0);
        if (lane < n) e = edges[base + lane];
        int j = 0;
        for (; j + 4 <= n; j += 4) {
            int c0 = __shfl(e.x, j);     float v0 = __int_as_float(__shfl(e.y, j));
            int c1 = __shfl(e.x, j + 1); float v1 = __int_as_float(__shfl(e.y, j + 1));
            int c2 = __shfl(e.x, j + 2); float v2 = __int_as_float(__shfl(e.y, j + 2));
            int c3 = __shfl(e.x, j + 3); float v3 = __int_as_float(__shfl(e.y, j + 3));
            float2 x0 = *((const float2*)(x + (size_t)c0 * DIM) + lane);
            float2 x1 = *((const float2*)(x + (size_t)c1 * DIM) + lane);
            float2 x2 = *((const float2*)(x + (size_t)c2 * DIM) + lane);
            float2 x3 = *((const float2*)(x + (size_t)c3 * DIM) + lane);
            a0 += v0 * x0.x; a1 += v0 * x0.y;
            a0 += v1 * x1.x; a1 += v1 * x1.y;
            a0 += v2 * x2.x; a1 += v2 * x2.y;
            a0 += v3 * x3.x; a1 += v3 * x3.y;
        }
        for (; j < n; j++) {
            int c = __shfl(e.x, j);
            float v = __int_as_float(__shfl(e.y, j));
            float2 xv = *((const float2*)(x + (size_t)c * DIM) + lane);
            a0 += v * xv.x; a1 += v * xv.y;
        }
    }
    size_t o2 = (size_t)w * (DIM / 2) + lane;  // float2 index
    if (out) ((float2*)out)[o2] = make_float2(a0, a1);  // normal: reused next kernel
    if (sum_out) {
        v2f s;
        if (sum_init) s = __builtin_nontemporal_load((const v2f*)sum_init + o2);
        else          s = __builtin_nontemporal_load((const v2f*)sum_out + o2);
        s.x += a0;
        s.y += a1;
        __builtin_nontemporal_store(s, (v2f*)sum_out + o2);
    }
}

// ---- gated GEMM: msg = concat(nm, nm*grp) @ W + b ;
//      edge_sum = (edge_init ? edge_init : edge_sum) + msg ---------------------
// block = 512 threads, 64 group rows x 128 cols of C per block.
// Register tile 4 rows x 4 cols (acc=16): the round-4 8x4 tile hit VGPR=216
// -> 8.8% occupancy -> latency-bound at VALUBusy 24%. Smaller tile +
// launch_bounds(512,4) caps VGPR at 128 -> 2-3 blocks/CU co-resident.
// Per kq: 8 ds_read_b128 feed 64 FMAs.
// NOTE: group_cur and msg_out may alias (each block reads only its own rows,
// all reads happen before the epilogue write) -> no __restrict__ on those.

__global__ __launch_bounds__(512, 4) void k_gemm_gate(const float* __restrict__ node_msg,
                                                      const float* group_cur,
                                                      const float* __restrict__ W,
                                                      const float* __restrict__ bias,
                                                      float* msg_out,
                                                      const float* __restrict__ edge_init,
                                                      float* __restrict__ edge_sum, int ng) {
    __shared__ float Wl[64][128];
    __shared__ float Xs[64][64];
    int t = threadIdx.x;
    int tc = t & 31;   // col quad: cols 4*tc .. 4*tc+3
    int tr = t >> 5;   // row quad: rows 4*tr .. 4*tr+3
    int g0 = blockIdx.x * 64;

    float acc[4][4];
#pragma unroll
    for (int r = 0; r < 4; r++)
#pragma unroll
        for (int c = 0; c < 4; c++) acc[r][c] = 0.f;

    for (int kc = 0; kc < 4; kc++) {
        int k0 = kc * 64;
        // stage W chunk: rows [k0, k0+64) x 128 cols, float4 granules
        for (int i = t; i < 64 * 32; i += 512) {
            int row = i >> 5, c4 = (i & 31) << 2;
            *(float4*)&Wl[row][c4] = *(const float4*)&W[(k0 + row) * 128 + c4];
        }
        // stage X chunk: 64 rows x 64 k (gate computed inline), float4 granules
        for (int i = t; i < 64 * 16; i += 512) {
            int r = i >> 4, k4 = (i & 15) << 2;
            int g = g0 + r;
            float4 v = make_float4(0.f, 0.f, 0.f, 0.f);
            if (g < ng) {
                if (k0 < 128) {
                    v = *(const float4*)&node_msg[g * 128 + k0 + k4];
                } else {
                    float4 a = *(const float4*)&node_msg[g * 128 + (k0 - 128) + k4];
                    float4 b = *(const float4*)(group_cur + g * 128 + (k0 - 128) + k4);
                    v = make_float4(a.x * b.x, a.y * b.y, a.z * b.z, a.w * b.w);
                }
            }
            *(float4*)&Xs[r][k4] = v;
        }
        __syncthreads();
#pragma unroll 4
        for (int kq = 0; kq < 16; kq++) {
            float4 w0 = *(float4*)&Wl[kq * 4 + 0][tc * 4];
            float4 w1 = *(float4*)&Wl[kq * 4 + 1][tc * 4];
            float4 w2 = *(float4*)&Wl[kq * 4 + 2][tc * 4];
            float4 w3 = *(float4*)&Wl[kq * 4 + 3][tc * 4];
#pragma unroll
            for (int ri = 0; ri < 4; ri++) {
                float4 xv = *(float4*)&Xs[tr * 4 + ri][kq * 4];
                acc[ri][0] += xv.x * w0.x + xv.y * w1.x + xv.z * w2.x + xv.w * w3.x;
                acc[ri][1] += xv.x * w0.y + xv.y * w1.y + xv.z * w2.y + xv.w * w3.y;
                acc[ri][2] += xv.x * w0.z + xv.y * w1.z + xv.z * w2.z + xv.w * w3.z;
                acc[ri][3] += xv.x * w0.w + xv.y * w1.w + xv.z * w2.w + xv.w * w3.w;
            }
        }
        __syncthreads();
    }

    float4 b4 = *(const float4*)&bias[tc * 4];
#pragma unroll
    for (int ri = 0; ri < 4; ri++) {
        int g = g0 + tr * 4 + ri;
        if (g < ng) {
            size_t idx = (size_t)g * 128 + tc * 4;
            v4f v;
            v.x = acc[ri][0] + b4.x; v.y = acc[ri][1] + b4.y;
            v.z = acc[ri][2] + b4.z; v.w = acc[ri][3] + b4.w;
            v4f es = edge_init
                ? __builtin_nontemporal_load((const v4f*)(edge_init + idx))
                : __builtin_nontemporal_load((const v4f*)(edge_sum + idx));
            *(v4f*)(msg_out + idx) = v;  // normal: gather source of next spmm
            __builtin_nontemporal_store(es + v, (v4f*)(edge_sum + idx));
        }
    }
}

// ---------------------------------------------------------------------------

extern "C" void kernel_launch(void* const* d_in, const int* in_sizes, int n_in,
                              void* d_out, int out_size, void* d_ws, size_t ws_size,
                              hipStream_t stream) {
    const float* group_emb = (const float*)d_in[0];  // [NG,128]
    const float* user_emb  = (const float*)d_in[1];  // [NU,128]
    const int*   rows      = (const int*)d_in[2];    // [NNZ]
    const int*   cols      = (const int*)d_in[3];    // [NNZ]
    const float* vals      = (const float*)d_in[4];  // [NNZ]
    const float* Ws        = (const float*)d_in[5];  // [3,256,128]
    const float* bs        = (const float*)d_in[6];  // [3,128]

    float* node_sum = (float*)d_out;                 // [NU,128]
    float* edge_sum = (float*)d_out + (size_t)NU * DIM;  // [NG,128]

    // workspace carve (16B aligned)
    char* p = (char*)d_ws;
    auto carve = [&](size_t bytes) {
        void* r = (void*)p;
        p += (bytes + 15) & ~(size_t)15;
        return r;
    };
    float* U        = (float*)carve((size_t)NU * DIM * 4);   // user ping buffer
    float* M        = (float*)carve((size_t)NG * DIM * 4);   // msg buffer
    float* node_msg = (float*)carve((size_t)NG * DIM * 4);
    int*   row_ptr  = (int*)carve((NG + 1) * 4);
    int*   col_ptr  = (int*)carve((NU + 1) * 4);
    int*   fillR    = (int*)carve(NBR * 4);
    int*   fillC    = (int*)carve(NBC * 4);
    int2*  r_edges  = (int2*)carve((size_t)NNZ * 8);
    int2*  c_edges  = (int2*)carve((size_t)NNZ * 8);
    int*   bktcnt   = (int*)carve((NBR + NBC) * 4);
    int*   baseR    = (int*)carve((NBR + 1) * 4);
    int*   baseC    = (int*)carve((NBC + 1) * 4);

    // binned staging buffers alias U: U is not live until the first layer,
    // and preprocessing finishes before the layers start. 2*NNZ*8 = 32MB
    // fits comfortably inside U's 102.4MB.
    int2* binR = (int2*)U;
    int2* binC = binR + NNZ;

    // --- build CSR (row-sorted) and CSC (col-sorted) packed edge lists ---
    hipMemsetAsync(bktcnt, 0, (NBR + NBC) * 4, stream);
    k_hist_coarse<<<256, 256, 0, stream>>>(rows, cols, bktcnt, NNZ);
    k_scanb<<<1, 1024, 0, stream>>>(bktcnt, baseR, baseC, fillR, fillC);
    k_bin<<<(NNZ + 256 * BIN_K - 1) / (256 * BIN_K), 256, 0, stream>>>(
        rows, cols, vals, fillR, fillC, binR, binC, NNZ);
    k_unbin<<<NBR + NBC, 256, 0, stream>>>(baseR, baseC, binR, binC,
                                           row_ptr, col_ptr, r_edges, c_edges);

    // --- layers (running-sum inits fused into layer-1 epilogues) ---
    for (int l = 0; l < LAYERS; l++) {
        const float* u_in = (l == 0) ? user_emb : U;
        const float* g_in = (l == 0) ? group_emb : M;

        // node_msg = H @ u_in
        k_spmm<<<(NG + 3) / 4, 256, 0, stream>>>(row_ptr, r_edges, u_in,
                                                 node_msg, nullptr, nullptr, NG);

        // M = concat(node_msg, node_msg*g_in) @ W + b ; edge_sum (+)= M
        k_gemm_gate<<<(NG + 63) / 64, 512, 0, stream>>>(
            node_msg, g_in, Ws + (size_t)l * 256 * 128, bs + (size_t)l * 128,
            M, (l == 0) ? group_emb : nullptr, edge_sum, NG);

        // U = H^T @ M ; node_sum (+)= U   (skip dead U store in last layer)
        k_spmm<<<(NU + 3) / 4, 256, 0, stream>>>(col_ptr, c_edges, M,
                                                 (l == LAYERS - 1) ? nullptr : U,
                                                 (l == 0) ? user_emb : nullptr,
                                                 node_sum, NU);
    }
}

// Round 6
// 1400.779 us; speedup vs baseline: 1.5235x; 1.0339x over previous
//
#include <hip/hip_runtime.h>
#include <hip/hip_bf16.h>

#define NG 50000
#define NU 200000
#define DIM 128
#define NNZ 2000000
#define LAYERS 3

// bucket geometry for the binned counting sort
#define RB_SHIFT 7                      // 128 rows per bucket
#define CB_SHIFT 9                      // 512 cols per bucket
#define NBR ((NG + 127) / 128)          // 391
#define NBC ((NU + 511) / 512)          // 391
#define BIN_K 32                        // edges per thread in k_bin (8192/block)

// native vector types for nontemporal builtins
typedef float v2f __attribute__((ext_vector_type(2)));
typedef float v4f __attribute__((ext_vector_type(4)));

// ---- coarse bucket histogram: LDS-aggregated ------------------------------

__global__ __launch_bounds__(256) void k_hist_coarse(const int* __restrict__ rows,
                                                     const int* __restrict__ cols,
                                                     int* __restrict__ bktcnt, int nnz) {
    __shared__ int cR[NBR];
    __shared__ int cC[NBC];
    int t = threadIdx.x;
    for (int i = t; i < NBR; i += 256) cR[i] = 0;
    for (int i = t; i < NBC; i += 256) cC[i] = 0;
    __syncthreads();
    int stride = gridDim.x * 256;
    for (int e = blockIdx.x * 256 + t; e < nnz; e += stride) {
        atomicAdd(&cR[rows[e] >> RB_SHIFT], 1);
        atomicAdd(&cC[cols[e] >> CB_SHIFT], 1);
    }
    __syncthreads();
    for (int i = t; i < NBR; i += 256) if (cR[i]) atomicAdd(&bktcnt[i], cR[i]);
    for (int i = t; i < NBC; i += 256) if (cC[i]) atomicAdd(&bktcnt[NBR + i], cC[i]);
}

// single-block scan of the 782 bucket counts -> bucket bases + k_bin seeds
__global__ __launch_bounds__(1024) void k_scanb(const int* __restrict__ bktcnt,
                                                int* __restrict__ baseR,
                                                int* __restrict__ baseC,
                                                int* __restrict__ fillR,
                                                int* __restrict__ fillC) {
    __shared__ int s[1024];
    int t = threadIdx.x;
    const int n = NBR + NBC;
    s[t] = (t < n) ? bktcnt[t] : 0;
    __syncthreads();
    for (int off = 1; off < 1024; off <<= 1) {
        int x = (t >= off) ? s[t - off] : 0;
        __syncthreads();
        s[t] += x;
        __syncthreads();
    }
    int excl = (t == 0) ? 0 : s[t - 1];
    if (t < NBR) { baseR[t] = excl; fillR[t] = excl; }
    else if (t < n) { int v = excl - NNZ; baseC[t - NBR] = v; fillC[t - NBR] = v; }
    if (t == 0) { baseR[NBR] = NNZ; baseC[NBC] = NNZ; }
}

// ---- pass 1: bin edges into bucket-contiguous staging arrays --------------
__global__ __launch_bounds__(256) void k_bin(const int* __restrict__ rows,
                                             const int* __restrict__ cols,
                                             const float* __restrict__ vals,
                                             int* __restrict__ fillR,
                                             int* __restrict__ fillC,
                                             int2* __restrict__ binR,
                                             int2* __restrict__ binC, int nnz) {
    __shared__ int cR[NBR];
    __shared__ int cC[NBC];
    int t = threadIdx.x;
    int base = blockIdx.x * (256 * BIN_K);
    for (int i = t; i < NBR; i += 256) cR[i] = 0;
    for (int i = t; i < NBC; i += 256) cC[i] = 0;
    __syncthreads();
    // count
    for (int k = 0; k < BIN_K; k++) {
        int e = base + k * 256 + t;
        if (e < nnz) {
            atomicAdd(&cR[rows[e] >> RB_SHIFT], 1);
            atomicAdd(&cC[cols[e] >> CB_SHIFT], 1);
        }
    }
    __syncthreads();
    for (int b = t; b < NBR; b += 256) {
        int n = cR[b];
        cR[b] = n ? atomicAdd(&fillR[b], n) : 0;
    }
    for (int b = t; b < NBC; b += 256) {
        int n = cC[b];
        cC[b] = n ? atomicAdd(&fillC[b], n) : 0;
    }
    __syncthreads();
    // write
    for (int k = 0; k < BIN_K; k++) {
        int e = base + k * 256 + t;
        if (e < nnz) {
            int r = rows[e], c = cols[e];
            int v = __float_as_int(vals[e]);
            int pR = atomicAdd(&cR[r >> RB_SHIFT], 1);
            binR[pR] = make_int2(((r & 127) << 18) | c, v);
            int pC = atomicAdd(&cC[c >> CB_SHIFT], 1);
            binC[pC] = make_int2(((c & 511) << 16) | r, v);
        }
    }
}

// ---- pass 2: per bucket: LDS hist -> wave scan -> write row_ptr/col_ptr ----
__global__ __launch_bounds__(256) void k_unbin(const int* __restrict__ baseR,
                                               const int* __restrict__ baseC,
                                               const int2* __restrict__ binR,
                                               const int2* __restrict__ binC,
                                               int* __restrict__ row_ptr,
                                               int* __restrict__ col_ptr,
                                               int2* __restrict__ r_edges,
                                               int2* __restrict__ c_edges) {
    __shared__ int pos[512];
    int t = threadIdx.x;
    int b = blockIdx.x;
    if (b < NBR) {
        int r0 = b << RB_SHIFT;
        int nr = min(128, NG - r0);
        int lo = baseR[b], hi = baseR[b + 1];
        if (t < 128) pos[t] = 0;
        __syncthreads();
        for (int i = lo + t; i < hi; i += 256)
            atomicAdd(&pos[binR[i].x >> 18], 1);
        __syncthreads();
        if (t < 64) {  // wave 0: exclusive scan of 128 counters, 2 per lane
            int lane = t;
            int i0 = lane * 2;
            int n0 = pos[i0], n1 = pos[i0 + 1];
            int s = n0 + n1;
            int v = s;
#pragma unroll
            for (int off = 1; off < 64; off <<= 1) {
                int u = __shfl_up(v, off);
                if (lane >= off) v += u;
            }
            int run = lo + (v - s);
            if (i0 < nr) row_ptr[r0 + i0] = run;
            pos[i0] = run; run += n0;
            if (i0 + 1 < nr) row_ptr[r0 + i0 + 1] = run;
            pos[i0 + 1] = run;
        }
        if (b == NBR - 1 && t == 0) row_ptr[NG] = NNZ;
        __syncthreads();
        for (int i = lo + t; i < hi; i += 256) {
            int2 e = binR[i];
            int lr = e.x >> 18;
            int c = e.x & 0x3FFFF;
            int p = atomicAdd(&pos[lr], 1);
            r_edges[p] = make_int2(c, e.y);
        }
    } else {
        int cb = b - NBR;
        int c0 = cb << CB_SHIFT;
        int nc = min(512, NU - c0);
        int lo = baseC[cb], hi = baseC[cb + 1];
        for (int i = t; i < 512; i += 256) pos[i] = 0;
        __syncthreads();
        for (int i = lo + t; i < hi; i += 256)
            atomicAdd(&pos[binC[i].x >> 16], 1);
        __syncthreads();
        if (t < 64) {  // wave 0: exclusive scan of 512 counters, 8 per lane
            int lane = t;
            int i0 = lane * 8;
            int n[8];
            int s = 0;
#pragma unroll
            for (int j = 0; j < 8; j++) { n[j] = pos[i0 + j]; s += n[j]; }
            int v = s;
#pragma unroll
            for (int off = 1; off < 64; off <<= 1) {
                int u = __shfl_up(v, off);
                if (lane >= off) v += u;
            }
            int run = lo + (v - s);
#pragma unroll
            for (int j = 0; j < 8; j++) {
                if (i0 + j < nc) col_ptr[c0 + i0 + j] = run;
                pos[i0 + j] = run;
                run += n[j];
            }
        }
        if (b == NBR + NBC - 1 && t == 0) col_ptr[NU] = NNZ;
        __syncthreads();
        for (int i = lo + t; i < hi; i += 256) {
            int2 e = binC[i];
            int lc = e.x >> 16;
            int r = e.x & 0xFFFF;
            int p = atomicAdd(&pos[lc], 1);
            c_edges[p] = make_int2(r, e.y);
        }
    }
}

// ---------------- SpMM: one wave per output row, float2 per lane -------------
// out[w] = sum_e val[e] * x[idx[e]]   (edges grouped by w via counting sort)
// optional fused: sum_out[w] = sum_init[w] + acc
// node_sum accumulation is DEFERRED via linearity (node_sum = user_emb +
// H^T(M1+M2+M3)), so the per-layer 204.8MB node_sum RMW stream is gone;
// layers 1-2 write only U, the final call fuses the user_emb init.

__global__ __launch_bounds__(256) void k_spmm(const int* __restrict__ ptr,
                                              const int2* __restrict__ edges,
                                              const float* __restrict__ x,
                                              float* __restrict__ out,
                                              const float* __restrict__ sum_init,
                                              float* __restrict__ sum_out,
                                              int nrows) {
    int w = blockIdx.x * 4 + (threadIdx.x >> 6);
    int lane = threadIdx.x & 63;
    if (w >= nrows) return;
    int beg = ptr[w], end = ptr[w + 1];
    float a0 = 0.f, a1 = 0.f;
    for (int base = beg; base < end; base += 64) {
        int n = end - base;
        if (n > 64) n = 64;
        int2 e = make_int2(0, 0);
        if (lane < n) e = edges[base + lane];
        int j = 0;
        for (; j + 4 <= n; j += 4) {
            int c0 = __shfl(e.x, j);     float v0 = __int_as_float(__shfl(e.y, j));
            int c1 = __shfl(e.x, j + 1); float v1 = __int_as_float(__shfl(e.y, j + 1));
            int c2 = __shfl(e.x, j + 2); float v2 = __int_as_float(__shfl(e.y, j + 2));
            int c3 = __shfl(e.x, j + 3); float v3 = __int_as_float(__shfl(e.y, j + 3));
            float2 x0 = *((const float2*)(x + (size_t)c0 * DIM) + lane);
            float2 x1 = *((const float2*)(x + (size_t)c1 * DIM) + lane);
            float2 x2 = *((const float2*)(x + (size_t)c2 * DIM) + lane);
            float2 x3 = *((const float2*)(x + (size_t)c3 * DIM) + lane);
            a0 += v0 * x0.x; a1 += v0 * x0.y;
            a0 += v1 * x1.x; a1 += v1 * x1.y;
            a0 += v2 * x2.x; a1 += v2 * x2.y;
            a0 += v3 * x3.x; a1 += v3 * x3.y;
        }
        for (; j < n; j++) {
            int c = __shfl(e.x, j);
            float v = __int_as_float(__shfl(e.y, j));
            float2 xv = *((const float2*)(x + (size_t)c * DIM) + lane);
            a0 += v * xv.x; a1 += v * xv.y;
        }
    }
    size_t o2 = (size_t)w * (DIM / 2) + lane;  // float2 index
    if (out) ((float2*)out)[o2] = make_float2(a0, a1);  // normal: reused next kernel
    if (sum_out) {
        v2f s = __builtin_nontemporal_load((const v2f*)sum_init + o2);
        s.x += a0;
        s.y += a1;
        __builtin_nontemporal_store(s, (v2f*)sum_out + o2);
    }
}

// ---- gated GEMM: msg = concat(nm, nm*grp) @ W + b ; Msum (+)= msg -----------
// block = 512 threads, 64 group rows x 128 cols of C per block, 4x4 reg tile.
// Msum accumulates M1+M2+M3 (lives in the edge_sum slot of d_out); the final
// edge_sum = group_emb + Msum is produced by k_addge after the last spmm.
// NOTE: group_cur and msg_out may alias (each block reads only its own rows,
// all reads happen before the epilogue write) -> no __restrict__ on those.

__global__ __launch_bounds__(512, 4) void k_gemm_gate(const float* __restrict__ node_msg,
                                                      const float* group_cur,
                                                      const float* __restrict__ W,
                                                      const float* __restrict__ bias,
                                                      float* msg_out,
                                                      float* __restrict__ msum,
                                                      int first, int ng) {
    __shared__ float Wl[64][128];
    __shared__ float Xs[64][64];
    int t = threadIdx.x;
    int tc = t & 31;   // col quad: cols 4*tc .. 4*tc+3
    int tr = t >> 5;   // row quad: rows 4*tr .. 4*tr+3
    int g0 = blockIdx.x * 64;

    float acc[4][4];
#pragma unroll
    for (int r = 0; r < 4; r++)
#pragma unroll
        for (int c = 0; c < 4; c++) acc[r][c] = 0.f;

    for (int kc = 0; kc < 4; kc++) {
        int k0 = kc * 64;
        // stage W chunk: rows [k0, k0+64) x 128 cols, float4 granules
        for (int i = t; i < 64 * 32; i += 512) {
            int row = i >> 5, c4 = (i & 31) << 2;
            *(float4*)&Wl[row][c4] = *(const float4*)&W[(k0 + row) * 128 + c4];
        }
        // stage X chunk: 64 rows x 64 k (gate computed inline), float4 granules
        for (int i = t; i < 64 * 16; i += 512) {
            int r = i >> 4, k4 = (i & 15) << 2;
            int g = g0 + r;
            float4 v = make_float4(0.f, 0.f, 0.f, 0.f);
            if (g < ng) {
                if (k0 < 128) {
                    v = *(const float4*)&node_msg[g * 128 + k0 + k4];
                } else {
                    float4 a = *(const float4*)&node_msg[g * 128 + (k0 - 128) + k4];
                    float4 b = *(const float4*)(group_cur + g * 128 + (k0 - 128) + k4);
                    v = make_float4(a.x * b.x, a.y * b.y, a.z * b.z, a.w * b.w);
                }
            }
            *(float4*)&Xs[r][k4] = v;
        }
        __syncthreads();
#pragma unroll 4
        for (int kq = 0; kq < 16; kq++) {
            float4 w0 = *(float4*)&Wl[kq * 4 + 0][tc * 4];
            float4 w1 = *(float4*)&Wl[kq * 4 + 1][tc * 4];
            float4 w2 = *(float4*)&Wl[kq * 4 + 2][tc * 4];
            float4 w3 = *(float4*)&Wl[kq * 4 + 3][tc * 4];
#pragma unroll
            for (int ri = 0; ri < 4; ri++) {
                float4 xv = *(float4*)&Xs[tr * 4 + ri][kq * 4];
                acc[ri][0] += xv.x * w0.x + xv.y * w1.x + xv.z * w2.x + xv.w * w3.x;
                acc[ri][1] += xv.x * w0.y + xv.y * w1.y + xv.z * w2.y + xv.w * w3.y;
                acc[ri][2] += xv.x * w0.z + xv.y * w1.z + xv.z * w2.z + xv.w * w3.z;
                acc[ri][3] += xv.x * w0.w + xv.y * w1.w + xv.z * w2.w + xv.w * w3.w;
            }
        }
        __syncthreads();
    }

    float4 b4 = *(const float4*)&bias[tc * 4];
#pragma unroll
    for (int ri = 0; ri < 4; ri++) {
        int g = g0 + tr * 4 + ri;
        if (g < ng) {
            size_t idx = (size_t)g * 128 + tc * 4;
            v4f v;
            v.x = acc[ri][0] + b4.x; v.y = acc[ri][1] + b4.y;
            v.z = acc[ri][2] + b4.z; v.w = acc[ri][3] + b4.w;
            v4f ms = first ? v : (*(const v4f*)(msum + idx) + v);
            *(v4f*)(msg_out + idx) = v;  // normal: gather source of next spmm
            *(v4f*)(msum + idx) = ms;
        }
    }
}

// edge_sum = Msum + group_emb (in place on the Msum/edge_sum slot of d_out)
__global__ __launch_bounds__(256) void k_addge(float* __restrict__ es,
                                               const float* __restrict__ ge) {
    const size_t n4 = (size_t)NG * DIM / 4;
    size_t stride = (size_t)gridDim.x * 256;
    for (size_t i = blockIdx.x * 256 + threadIdx.x; i < n4; i += stride) {
        v4f a = *((const v4f*)es + i);
        v4f b = *((const v4f*)ge + i);
        *((v4f*)es + i) = a + b;
    }
}

// ---------------------------------------------------------------------------

extern "C" void kernel_launch(void* const* d_in, const int* in_sizes, int n_in,
                              void* d_out, int out_size, void* d_ws, size_t ws_size,
                              hipStream_t stream) {
    const float* group_emb = (const float*)d_in[0];  // [NG,128]
    const float* user_emb  = (const float*)d_in[1];  // [NU,128]
    const int*   rows      = (const int*)d_in[2];    // [NNZ]
    const int*   cols      = (const int*)d_in[3];    // [NNZ]
    const float* vals      = (const float*)d_in[4];  // [NNZ]
    const float* Ws        = (const float*)d_in[5];  // [3,256,128]
    const float* bs        = (const float*)d_in[6];  // [3,128]

    float* node_sum = (float*)d_out;                 // [NU,128]
    float* msum     = (float*)d_out + (size_t)NU * DIM;  // Msum, becomes edge_sum

    // workspace carve (16B aligned)
    char* p = (char*)d_ws;
    auto carve = [&](size_t bytes) {
        void* r = (void*)p;
        p += (bytes + 15) & ~(size_t)15;
        return r;
    };
    float* U        = (float*)carve((size_t)NU * DIM * 4);   // user ping buffer
    float* M        = (float*)carve((size_t)NG * DIM * 4);   // msg buffer
    float* node_msg = (float*)carve((size_t)NG * DIM * 4);
    int*   row_ptr  = (int*)carve((NG + 1) * 4);
    int*   col_ptr  = (int*)carve((NU + 1) * 4);
    int*   fillR    = (int*)carve(NBR * 4);
    int*   fillC    = (int*)carve(NBC * 4);
    int2*  r_edges  = (int2*)carve((size_t)NNZ * 8);
    int2*  c_edges  = (int2*)carve((size_t)NNZ * 8);
    int*   bktcnt   = (int*)carve((NBR + NBC) * 4);
    int*   baseR    = (int*)carve((NBR + 1) * 4);
    int*   baseC    = (int*)carve((NBC + 1) * 4);

    // binned staging buffers alias U (U not live during preprocessing)
    int2* binR = (int2*)U;
    int2* binC = binR + NNZ;

    // --- build CSR (row-sorted) and CSC (col-sorted) packed edge lists ---
    hipMemsetAsync(bktcnt, 0, (NBR + NBC) * 4, stream);
    k_hist_coarse<<<256, 256, 0, stream>>>(rows, cols, bktcnt, NNZ);
    k_scanb<<<1, 1024, 0, stream>>>(bktcnt, baseR, baseC, fillR, fillC);
    k_bin<<<(NNZ + 256 * BIN_K - 1) / (256 * BIN_K), 256, 0, stream>>>(
        rows, cols, vals, fillR, fillC, binR, binC, NNZ);
    k_unbin<<<NBR + NBC, 256, 0, stream>>>(baseR, baseC, binR, binC,
                                           row_ptr, col_ptr, r_edges, c_edges);

    // --- layers ---
    // node_sum = user_emb + H^T(M1+M2+M3)  (deferred, one fused spmm at end)
    // edge_sum = group_emb + (M1+M2+M3)    (cheap k_addge at end)
    for (int l = 0; l < LAYERS; l++) {
        const float* u_in = (l == 0) ? user_emb : U;
        const float* g_in = (l == 0) ? group_emb : M;

        // node_msg = H @ u_in
        k_spmm<<<(NG + 3) / 4, 256, 0, stream>>>(row_ptr, r_edges, u_in,
                                                 node_msg, nullptr, nullptr, NG);

        // M = concat(node_msg, node_msg*g_in) @ W + b ; Msum (+)= M
        k_gemm_gate<<<(NG + 63) / 64, 512, 0, stream>>>(
            node_msg, g_in, Ws + (size_t)l * 256 * 128, bs + (size_t)l * 128,
            M, msum, (l == 0) ? 1 : 0, NG);

        // U = H^T @ M (needed as next layer's input; skip in last layer)
        if (l < LAYERS - 1)
            k_spmm<<<(NU + 3) / 4, 256, 0, stream>>>(col_ptr, c_edges, M,
                                                     U, nullptr, nullptr, NU);
    }

    // node_sum = user_emb + H^T @ Msum
    k_spmm<<<(NU + 3) / 4, 256, 0, stream>>>(col_ptr, c_edges, msum,
                                             nullptr, user_emb, node_sum, NU);
    // edge_sum = Msum + group_emb (in place)
    k_addge<<<1024, 256, 0, stream>>>(msum, group_emb);
}